// Round 8
// baseline (387.993 us; speedup 1.0000x reference)
//
#include <hip/hip_runtime.h>
#include <hip/hip_bf16.h>
#include <math.h>

#define N_HEADN 100000
#define N_TAILN 100000
#define NEDGE   1600000
#define SLOPE   0.2f

#define NB   196      // buckets: head>>9
#define HPB  512      // heads per bucket
#define BCAP 9216     // bucket capacity (mean 8163, sigma ~90; +11 sigma)

static __device__ __forceinline__ float bf2f(__hip_bfloat16 x) { return __bfloat162float(x); }

// ---------------- k0: wl[128][4], he[8][4]  (fp32 in) ----------------
__global__ void k0_prep(const float* __restrict__ W,
                        const float* __restrict__ W_e,
                        const float* __restrict__ a_l,
                        const float* __restrict__ a_e,
                        const float* __restrict__ emb,
                        float* __restrict__ wl, float* __restrict__ he) {
  const int t = threadIdx.x;  // 128 threads
  #pragma unroll
  for (int h = 0; h < 4; ++h) {
    float sl = 0.f;
    for (int d = 0; d < 32; ++d)
      sl += W[t * 128 + h * 32 + d] * a_l[h * 32 + d];
    wl[t * 4 + h] = sl;
  }
  if (t < 32) {
    const int et = t >> 2, h = t & 3;
    float acc = 0.f;
    for (int d = 0; d < 32; ++d) {
      float tmp = 0.f;
      for (int f = 0; f < 32; ++f)
        tmp += emb[et * 32 + f] * W_e[f * 128 + h * 32 + d];
      acc += a_e[h * 32 + d] * tmp;
    }
    he[et * 4 + h] = acc;
  }
}

// ---------------- k0w: W fp32 -> bf16 ----------------
__global__ __launch_bounds__(256) void k0w(const float* __restrict__ W,
                                           __hip_bfloat16* __restrict__ Wb) {
  const int i = (blockIdx.x * 256 + threadIdx.x) * 4;
  const float4 v = *(const float4*)&W[i];
  union { unsigned short us[4]; uint2 u2; } pk;
  __hip_bfloat16 b0 = __float2bfloat16(v.x); pk.us[0] = *(unsigned short*)&b0;
  __hip_bfloat16 b1 = __float2bfloat16(v.y); pk.us[1] = *(unsigned short*)&b1;
  __hip_bfloat16 b2 = __float2bfloat16(v.z); pk.us[2] = *(unsigned short*)&b2;
  __hip_bfloat16 b3 = __float2bfloat16(v.w); pk.us[3] = *(unsigned short*)&b3;
  *(uint2*)&Wb[i] = pk.u2;
}

// ---------------- k1: h_l = head @ wl  (wave per node) ----------------
__global__ __launch_bounds__(256) void k1_hlr(const float* __restrict__ feat,
                                              const float* __restrict__ wv,
                                              float* __restrict__ o, int n) {
  const int gid = blockIdx.x * 256 + threadIdx.x;
  const int node = gid >> 6, lane = gid & 63;
  if (node >= n) return;
  const float* row = feat + (size_t)node * 128;
  const float x0 = row[lane];
  const float x1 = row[lane + 64];
  const float4 w0 = *(const float4*)(wv + lane * 4);
  const float4 w1 = *(const float4*)(wv + (lane + 64) * 4);
  float p0 = x0 * w0.x + x1 * w1.x;
  float p1 = x0 * w0.y + x1 * w1.y;
  float p2 = x0 * w0.z + x1 * w1.z;
  float p3 = x0 * w0.w + x1 * w1.w;
  #pragma unroll
  for (int m = 32; m; m >>= 1) {
    p0 += __shfl_xor(p0, m, 64);
    p1 += __shfl_xor(p1, m, 64);
    p2 += __shfl_xor(p2, m, 64);
    p3 += __shfl_xor(p3, m, 64);
  }
  if (lane == 0) *(float4*)(o + (size_t)node * 4) = make_float4(p0, p1, p2, p3);
}

// ---------------- k2: h_tail = tail @ W (bf16) + h_r from epilogue ----------------
__global__ __launch_bounds__(256) void k2_gemm(const float* __restrict__ A,
                                               const __hip_bfloat16* __restrict__ Wb,
                                               const float* __restrict__ a_r,
                                               __hip_bfloat16* __restrict__ out,
                                               float* __restrict__ h_r) {
  __shared__ __hip_bfloat16 sW[128 * 128];   // [k][c]
  __shared__ __hip_bfloat16 sA[128 * 68];    // [k][r]
  const int t = threadIdx.x;
  {
    const uint4* src = (const uint4*)Wb;
    uint4* dst = (uint4*)sW;
    #pragma unroll
    for (int i = 0; i < 8; ++i) dst[i * 256 + t] = src[i * 256 + t];
  }
  const int r0 = blockIdx.x * 64;
  #pragma unroll
  for (int ii = 0; ii < 8; ++ii) {
    const int i = ii * 256 + t;
    const int r = i >> 5, k4 = (i & 31) * 4;
    float4 v = make_float4(0.f, 0.f, 0.f, 0.f);
    if (r0 + r < N_TAILN) v = *(const float4*)&A[(size_t)(r0 + r) * 128 + k4];
    sA[(k4 + 0) * 68 + r] = __float2bfloat16(v.x);
    sA[(k4 + 1) * 68 + r] = __float2bfloat16(v.y);
    sA[(k4 + 2) * 68 + r] = __float2bfloat16(v.z);
    sA[(k4 + 3) * 68 + r] = __float2bfloat16(v.w);
  }
  __syncthreads();

  const int tc = t & 15, tr = t >> 4;
  const int c8 = tc * 8, r4 = tr * 4;
  float acc[4][8];
  #pragma unroll
  for (int i = 0; i < 4; ++i)
    #pragma unroll
    for (int j = 0; j < 8; ++j) acc[i][j] = 0.f;

  #pragma unroll 2
  for (int k = 0; k < 128; ++k) {
    const uint2 ab = *(const uint2*)&sA[k * 68 + r4];
    const float ar[4] = {__uint_as_float(ab.x << 16), __uint_as_float(ab.x & 0xffff0000u),
                         __uint_as_float(ab.y << 16), __uint_as_float(ab.y & 0xffff0000u)};
    const uint4 wbv = *(const uint4*)&sW[k * 128 + c8];
    float w[8];
    w[0] = __uint_as_float(wbv.x << 16); w[1] = __uint_as_float(wbv.x & 0xffff0000u);
    w[2] = __uint_as_float(wbv.y << 16); w[3] = __uint_as_float(wbv.y & 0xffff0000u);
    w[4] = __uint_as_float(wbv.z << 16); w[5] = __uint_as_float(wbv.z & 0xffff0000u);
    w[6] = __uint_as_float(wbv.w << 16); w[7] = __uint_as_float(wbv.w & 0xffff0000u);
    #pragma unroll
    for (int i = 0; i < 4; ++i)
      #pragma unroll
      for (int j = 0; j < 8; ++j)
        acc[i][j] += ar[i] * w[j];
  }

  const int hh = tc >> 2, d0 = (tc & 3) * 8;
  const float4 ar0 = *(const float4*)&a_r[hh * 32 + d0];
  const float4 ar1 = *(const float4*)&a_r[hh * 32 + d0 + 4];
  #pragma unroll
  for (int i = 0; i < 4; ++i) {
    float hr = acc[i][0] * ar0.x + acc[i][1] * ar0.y + acc[i][2] * ar0.z + acc[i][3] * ar0.w
             + acc[i][4] * ar1.x + acc[i][5] * ar1.y + acc[i][6] * ar1.z + acc[i][7] * ar1.w;
    hr += __shfl_xor(hr, 1, 64);
    hr += __shfl_xor(hr, 2, 64);
    if ((tc & 3) == 0 && (r0 + r4 + i) < N_TAILN)
      h_r[(size_t)(r0 + r4 + i) * 4 + hh] = hr;
  }

  #pragma unroll
  for (int i = 0; i < 4; ++i) {
    const int rr = r0 + r4 + i;
    if (rr < N_TAILN) {
      union { unsigned short us[8]; uint4 u4; } pk;
      #pragma unroll
      for (int j = 0; j < 8; ++j) {
        __hip_bfloat16 b = __float2bfloat16(acc[i][j]);
        pk.us[j] = *(unsigned short*)&b;
      }
      *(uint4*)&out[(size_t)rr * 128 + c8] = pk.u4;
    }
  }
}

// ---------------- p1: partition edges into 196 head-buckets (4B records) ----------------
// record = ti | et<<17 | hlocal<<20
__global__ __launch_bounds__(256) void p1_part(const int* __restrict__ head_ind,
                                               const int* __restrict__ tail_ind,
                                               const int* __restrict__ etype,
                                               int* __restrict__ bucketCursor,
                                               unsigned int* __restrict__ recs) {
  __shared__ int hist[NB];
  const int t = threadIdx.x;
  for (int i = t; i < NB; i += 256) hist[i] = 0;
  __syncthreads();
  const int e0 = blockIdx.x * 6400;                  // 250 blocks x 6400 = 1.6M
  int h[25];
  #pragma unroll
  for (int i = 0; i < 25; ++i) {
    h[i] = head_ind[e0 + i * 256 + t];
    atomicAdd(&hist[h[i] >> 9], 1);
  }
  __syncthreads();
  for (int i = t; i < NB; i += 256) {
    const int c = hist[i];
    hist[i] = atomicAdd(&bucketCursor[i], c);        // hist becomes running cursor
  }
  __syncthreads();
  #pragma unroll
  for (int i = 0; i < 25; ++i) {
    const int e = e0 + i * 256 + t;
    const int hi = h[i];
    const int b = hi >> 9;
    const int pos = atomicAdd(&hist[b], 1);
    recs[b * BCAP + pos] = (unsigned)tail_ind[e] | ((unsigned)etype[e] << 17)
                         | ((unsigned)(hi & 511) << 20);
  }
}

// ---------------- bscan: exclusive scan of 196 bucket counts (1 block) ----------------
__global__ __launch_bounds__(256) void bscan(const int* __restrict__ bucketCursor,
                                             int* __restrict__ bucketBase) {
  __shared__ int sm[256];
  const int t = threadIdx.x;
  const int v = (t < NB) ? bucketCursor[t] : 0;
  sm[t] = v;
  __syncthreads();
  for (int st = 1; st < 256; st <<= 1) {
    const int add = (t >= st) ? sm[t - st] : 0;
    __syncthreads();
    sm[t] += add;
    __syncthreads();
  }
  if (t < NB) bucketBase[t] = sm[t] - v;   // exclusive
}

// ---------------- p2_off: per-head hist + in-block scan -> off directly ----------------
__global__ __launch_bounds__(256) void p2_off(const unsigned int* __restrict__ recs,
                                              const int* __restrict__ bucketCursor,
                                              const int* __restrict__ bucketBase,
                                              int* __restrict__ off) {
  __shared__ int hist[HPB];
  __shared__ int tmp[256];
  const int b = blockIdx.x, t = threadIdx.x;
  hist[2 * t] = 0; hist[2 * t + 1] = 0;
  __syncthreads();
  const int cnt = bucketCursor[b];
  for (int i = t; i < cnt; i += 256)
    atomicAdd(&hist[recs[b * BCAP + i] >> 20], 1);
  __syncthreads();
  const int v0 = hist[2 * t], v1 = hist[2 * t + 1];
  tmp[t] = v0 + v1;
  __syncthreads();
  for (int st = 1; st < 256; st <<= 1) {
    const int add = (t >= st) ? tmp[t - st] : 0;
    __syncthreads();
    tmp[t] += add;
    __syncthreads();
  }
  const int base = bucketBase[b];
  const int excl = base + tmp[t] - (v0 + v1);
  const int h0 = b * HPB;
  if (h0 + 2 * t     <= N_HEADN) off[h0 + 2 * t]     = excl;
  if (h0 + 2 * t + 1 <= N_HEADN) off[h0 + 2 * t + 1] = excl + v0;
}

// ---------------- p3: bucket -> CSR scatter with LDS cursors ----------------
__global__ __launch_bounds__(256) void p3_scatter(const unsigned int* __restrict__ recs,
                                                  const int* __restrict__ bucketCursor,
                                                  const int* __restrict__ off,
                                                  int* __restrict__ pt) {
  __shared__ int cur[HPB];
  const int b = blockIdx.x, t = threadIdx.x;
  const int h0 = b * HPB;
  for (int i = t; i < HPB; i += 256)
    cur[i] = (h0 + i < N_HEADN) ? off[h0 + i] : 0;
  __syncthreads();
  const int cnt = bucketCursor[b];
  for (int i = t; i < cnt; i += 256) {
    const unsigned r = recs[b * BCAP + i];
    const int pos = atomicAdd(&cur[r >> 20], 1);
    pt[pos] = (int)(r & 0xFFFFFu);                   // ti | et<<17
  }
}

// ---------------- k4: online softmax + aggregation (2 edges/iter gather) ----------------
__global__ __launch_bounds__(256) void k4_agg(const int* __restrict__ off,
                                              const int* __restrict__ pt,
                                              const float* __restrict__ h_l,
                                              const float* __restrict__ h_r,
                                              const float* __restrict__ he,
                                              const __hip_bfloat16* __restrict__ h_tail,
                                              float* __restrict__ out) {
  __shared__ __align__(16) float sw[4][64][4];
  __shared__ int sti[4][64];
  __shared__ float she[32];
  const int wid = threadIdx.x >> 6;
  const int lane = threadIdx.x & 63;
  if (threadIdx.x < 32) she[threadIdx.x] = he[threadIdx.x];
  __syncthreads();                                  // only block barrier: she visibility
  const int n = blockIdx.x * 4 + wid;               // grid exact: 25000*4
  const int s = off[n], e = off[n + 1];
  const int nch = (e - s + 63) >> 6;
  const float4 hl = *(const float4*)(h_l + (size_t)n * 4);
  const int p  = lane >> 5;                         // edge parity in gather
  const int lc = lane & 31;                         // col group: dims 4*lc..4*lc+3
  const int hg = lc >> 3;                           // head of my cols
  float m0 = -1e30f, m1 = -1e30f, m2 = -1e30f, m3 = -1e30f;
  float s0 = 0.f, s1 = 0.f, s2 = 0.f, s3 = 0.f;
  float a0c = 0.f, a1c = 0.f, a2c = 0.f, a3c = 0.f; // 4 col accumulators
  for (int c = 0; c < nch; ++c) {                   // waves fully independent
    const int base = s + (c << 6);
    const int rem = min(64, e - base);
    float a0 = -1e30f, a1 = -1e30f, a2 = -1e30f, a3 = -1e30f;
    if (lane < rem) {                               // softmax: lane = edge idx
      const int pk = pt[base + lane];
      const int ti = pk & 0x1FFFF;
      const int et = pk >> 17;
      const float4 hr = *(const float4*)(h_r + (size_t)ti * 4);
      a0 = hl.x + hr.x + she[et * 4 + 0];
      a1 = hl.y + hr.y + she[et * 4 + 1];
      a2 = hl.z + hr.z + she[et * 4 + 2];
      a3 = hl.w + hr.w + she[et * 4 + 3];
      a0 = a0 > 0.f ? a0 : SLOPE * a0;
      a1 = a1 > 0.f ? a1 : SLOPE * a1;
      a2 = a2 > 0.f ? a2 : SLOPE * a2;
      a3 = a3 > 0.f ? a3 : SLOPE * a3;
      sti[wid][lane] = ti;
    }
    float c0 = a0, c1 = a1, c2 = a2, c3 = a3;
    #pragma unroll
    for (int msk = 32; msk; msk >>= 1) {
      c0 = fmaxf(c0, __shfl_xor(c0, msk, 64));
      c1 = fmaxf(c1, __shfl_xor(c1, msk, 64));
      c2 = fmaxf(c2, __shfl_xor(c2, msk, 64));
      c3 = fmaxf(c3, __shfl_xor(c3, msk, 64));
    }
    const float nm0 = fmaxf(m0, c0), nm1 = fmaxf(m1, c1);
    const float nm2 = fmaxf(m2, c2), nm3 = fmaxf(m3, c3);
    const float e0 = __expf(m0 - nm0), e1 = __expf(m1 - nm1);
    const float e2 = __expf(m2 - nm2), e3 = __expf(m3 - nm3);
    const float w0 = __expf(a0 - nm0), w1 = __expf(a1 - nm1);
    const float w2 = __expf(a2 - nm2), w3 = __expf(a3 - nm3);
    float t0 = w0, t1 = w1, t2 = w2, t3 = w3;
    #pragma unroll
    for (int msk = 32; msk; msk >>= 1) {
      t0 += __shfl_xor(t0, msk, 64);
      t1 += __shfl_xor(t1, msk, 64);
      t2 += __shfl_xor(t2, msk, 64);
      t3 += __shfl_xor(t3, msk, 64);
    }
    s0 = s0 * e0 + t0; s1 = s1 * e1 + t1;
    s2 = s2 * e2 + t2; s3 = s3 * e3 + t3;
    m0 = nm0; m1 = nm1; m2 = nm2; m3 = nm3;
    *(float4*)&sw[wid][lane][0] = make_float4(w0, w1, w2, w3);
    const float sc = (hg == 0) ? e0 : (hg == 1) ? e1 : (hg == 2) ? e2 : e3;
    a0c *= sc; a1c *= sc; a2c *= sc; a3c *= sc;
    __builtin_amdgcn_wave_barrier();
    {
      const __hip_bfloat16* __restrict__ rb = h_tail + lc * 4;  // + ti*128 per edge
      int jb = 0;
      for (; jb + 8 <= rem; jb += 8) {              // 4 pairs: 8 edges, 4 loads in flight
        const int j0 = jb + p, j1 = jb + 2 + p, j2 = jb + 4 + p, j3 = jb + 6 + p;
        const int   i0 = sti[wid][j0], i1 = sti[wid][j1];
        const int   i2 = sti[wid][j2], i3 = sti[wid][j3];
        const float q0 = sw[wid][j0][hg], q1 = sw[wid][j1][hg];
        const float q2 = sw[wid][j2][hg], q3 = sw[wid][j3][hg];
        const uint2 v0 = *(const uint2*)(rb + (unsigned)i0 * 128);
        const uint2 v1 = *(const uint2*)(rb + (unsigned)i1 * 128);
        const uint2 v2 = *(const uint2*)(rb + (unsigned)i2 * 128);
        const uint2 v3 = *(const uint2*)(rb + (unsigned)i3 * 128);
        a0c += q0 * __uint_as_float(v0.x << 16);          a1c += q0 * __uint_as_float(v0.x & 0xffff0000u);
        a2c += q0 * __uint_as_float(v0.y << 16);          a3c += q0 * __uint_as_float(v0.y & 0xffff0000u);
        a0c += q1 * __uint_as_float(v1.x << 16);          a1c += q1 * __uint_as_float(v1.x & 0xffff0000u);
        a2c += q1 * __uint_as_float(v1.y << 16);          a3c += q1 * __uint_as_float(v1.y & 0xffff0000u);
        a0c += q2 * __uint_as_float(v2.x << 16);          a1c += q2 * __uint_as_float(v2.x & 0xffff0000u);
        a2c += q2 * __uint_as_float(v2.y << 16);          a3c += q2 * __uint_as_float(v2.y & 0xffff0000u);
        a0c += q3 * __uint_as_float(v3.x << 16);          a1c += q3 * __uint_as_float(v3.x & 0xffff0000u);
        a2c += q3 * __uint_as_float(v3.y << 16);          a3c += q3 * __uint_as_float(v3.y & 0xffff0000u);
      }
      for (; jb < rem; jb += 2) {                   // tail pairs
        const int j = jb + p;
        if (j < rem) {
          const int   ii = sti[wid][j];
          const float qq = sw[wid][j][hg];
          const uint2 vv = *(const uint2*)(rb + (unsigned)ii * 128);
          a0c += qq * __uint_as_float(vv.x << 16);        a1c += qq * __uint_as_float(vv.x & 0xffff0000u);
          a2c += qq * __uint_as_float(vv.y << 16);        a3c += qq * __uint_as_float(vv.y & 0xffff0000u);
        }
      }
    }
    __builtin_amdgcn_wave_barrier();
  }
  // merge parities
  a0c += __shfl_xor(a0c, 32, 64);
  a1c += __shfl_xor(a1c, 32, 64);
  a2c += __shfl_xor(a2c, 32, 64);
  a3c += __shfl_xor(a3c, 32, 64);
  const float denom = (hg == 0) ? s0 : (hg == 1) ? s1 : (hg == 2) ? s2 : s3;
  const float inv = denom > 0.f ? 1.f / denom : 0.f;
  float o0 = a0c * inv, o1 = a1c * inv, o2 = a2c * inv, o3 = a3c * inv;
  o0 = o0 > 0.f ? o0 : expm1f(o0);
  o1 = o1 > 0.f ? o1 : expm1f(o1);
  o2 = o2 > 0.f ? o2 : expm1f(o2);
  o3 = o3 > 0.f ? o3 : expm1f(o3);
  if (p == 0)
    *(float4*)(out + (size_t)n * 128 + lc * 4) = make_float4(o0, o1, o2, o3);
}

extern "C" void kernel_launch(void* const* d_in, const int* in_sizes, int n_in,
                              void* d_out, int out_size, void* d_ws, size_t ws_size,
                              hipStream_t stream) {
  const float* head = (const float*)d_in[0];
  const float* tail = (const float*)d_in[1];
  const int* elist  = (const int*)d_in[2];
  const int* etype  = (const int*)d_in[3];
  const float* W    = (const float*)d_in[4];
  const float* W_e  = (const float*)d_in[5];
  const float* a_l  = (const float*)d_in[6];
  const float* a_r  = (const float*)d_in[7];
  const float* a_e  = (const float*)d_in[8];
  const float* emb  = (const float*)d_in[9];
  const int* head_ind = elist;
  const int* tail_ind = elist + NEDGE;
  (void)in_sizes; (void)n_in; (void)out_size; (void)ws_size;

  char* p = (char*)d_ws;
  size_t o = 0;
  auto carve = [&](size_t bytes) {
    char* r = p + o;
    o += (bytes + 255) & ~(size_t)255;
    return r;
  };
  // total ~43 MB
  __hip_bfloat16* h_tail = (__hip_bfloat16*)carve((size_t)N_TAILN * 128 * 2);  // 25.6 MB
  int*   pt     = (int*)   carve((size_t)NEDGE * 4);                            // 6.4 MB
  unsigned int* recs = (unsigned int*)carve((size_t)NB * BCAP * 4);             // 7.2 MB
  float* h_l    = (float*) carve((size_t)N_HEADN * 4 * 4);                      // 1.6 MB
  float* h_r    = (float*) carve((size_t)N_TAILN * 4 * 4);                      // 1.6 MB
  int*   off    = (int*)   carve((size_t)(N_HEADN + 1) * 4);                    // 0.4 MB
  int*   bucketCursor = (int*)carve(NB * 4);
  int*   bucketBase   = (int*)carve(NB * 4);
  float* wl     = (float*) carve(128 * 4 * 4);
  float* he     = (float*) carve(8 * 4 * 4);
  __hip_bfloat16* Wb = (__hip_bfloat16*)carve(16384 * 2);                       // 32 KB

  hipMemsetAsync(bucketCursor, 0, NB * sizeof(int), stream);
  k0_prep<<<1, 128, 0, stream>>>(W, W_e, a_l, a_e, emb, wl, he);
  k0w<<<16, 256, 0, stream>>>(W, Wb);
  k1_hlr<<<(N_HEADN * 64) / 256, 256, 0, stream>>>(head, wl, h_l, N_HEADN);
  k2_gemm<<<(N_TAILN + 63) / 64, 256, 0, stream>>>(tail, Wb, a_r, h_tail, h_r);
  p1_part<<<NEDGE / 6400, 256, 0, stream>>>(head_ind, tail_ind, etype, bucketCursor, recs);
  bscan<<<1, 256, 0, stream>>>(bucketCursor, bucketBase);
  p2_off<<<NB, 256, 0, stream>>>(recs, bucketCursor, bucketBase, off);
  p3_scatter<<<NB, 256, 0, stream>>>(recs, bucketCursor, off, pt);
  k4_agg<<<N_HEADN / 4, 256, 0, stream>>>(off, pt, h_l, h_r, he, h_tail, (float*)d_out);
}